// Round 12
// baseline (722.548 us; speedup 1.0000x reference)
//
#include <hip/hip_runtime.h>

// DAG-GRU encoder v3: batch-split interleaved persistent kernel.
// B=16, S=64, H=1024, C=16. 256 blocks x 512 thr; block = 4-o tile x 16 b.
// Batches split into 2 groups (b0-7, b8-15) with independent flags/exchange;
// per step the schedule A(g0),A(g1),B(g0),B(g1) hides each group's sync RTT
// behind the other group's compute (batch chains are independent).
// Weights 20 VGPR/lane (zero replication, no spill — r10/r11 verified).
// Sync: single-writer flags per group via IF-coherent (sc0 sc1) ops, r8
// protocol; publish+flag kept in wave 0 (per-wave vmcnt acks all lanes).
// kF: separate kernel computes mu/logvar from validated f32 hv in out.

#define NT 512
#define NBLK 256

typedef unsigned int uint;
typedef __attribute__((ext_vector_type(2))) _Float16 half2v;
typedef __attribute__((ext_vector_type(2))) uint uint2v;
typedef __attribute__((ext_vector_type(4))) uint uint4v;
typedef __attribute__((ext_vector_type(4))) int int4v;

__device__ __forceinline__ float fdot2(uint w, uint h, float acc) {
#if __has_builtin(__builtin_amdgcn_fdot2)
    return __builtin_amdgcn_fdot2(__builtin_bit_cast(half2v, w),
                                  __builtin_bit_cast(half2v, h), acc, false);
#else
    half2v a = __builtin_bit_cast(half2v, w);
    half2v b = __builtin_bit_cast(half2v, h);
    return acc + (float)a[0] * (float)b[0] + (float)a[1] * (float)b[1];
#endif
}

__device__ __forceinline__ uint packh2(float a, float b) {
    half2v h; h[0] = (_Float16)a; h[1] = (_Float16)b;
    return __builtin_bit_cast(uint, h);
}

__device__ __forceinline__ float sigm(float x) { return 1.0f / (1.0f + __expf(-x)); }
__device__ __forceinline__ float tanhfast(float x) { return 2.0f / (1.0f + __expf(-2.0f * x)) - 1.0f; }

// stage one group's exchange vector (4096 uints = 16KB) to LDS, conflict-free
__device__ __forceinline__ void stage2(const uint* src, uint* lds, int tid) {
    const uint* a0 = src + tid * 4;
    const uint* a1 = a0 + 2048;
    uint4v u0, u1;
    asm volatile("global_load_dwordx4 %0, %2, off sc0 sc1\n\t"
                 "global_load_dwordx4 %1, %3, off sc0 sc1\n\t"
                 "s_waitcnt vmcnt(0)"
                 : "=&v"(u0), "=&v"(u1) : "v"(a0), "v"(a1) : "memory");
    *(uint4v*)(lds + tid * 4)        = u0;
    *(uint4v*)(lds + tid * 4 + 2048) = u1;
}

__device__ __forceinline__ void st_dev2_wait(uint* p, uint lo, uint hi) {
    uint2v v; v[0] = lo; v[1] = hi;
    asm volatile("global_store_dwordx2 %0, %1, off sc0 sc1\n\ts_waitcnt vmcnt(0)"
                 :: "v"(p), "v"(v) : "memory");
}
__device__ __forceinline__ void st_flag_noack(int* p, int v) {
    asm volatile("global_store_dword %0, %1, off sc0 sc1" :: "v"(p), "v"(v) : "memory");
}

// poll one group's 256 single-writer flags (4 per lane of wave 0) until >= gen
__device__ __forceinline__ void wait_flags(const int* fl, int gen) {
    if (threadIdx.x < 64) {
        const int* pp = fl + threadIdx.x * 4;
        bool done;
        do {
            int4v v;
            asm volatile("global_load_dwordx4 %0, %1, off sc0 sc1\n\ts_waitcnt vmcnt(0)"
                         : "=v"(v) : "v"(pp) : "memory");
            done = __all(v[0] >= gen && v[1] >= gen && v[2] >= gen && v[3] >= gen);
        } while (!done);
    }
    __syncthreads();
}

__device__ __forceinline__ void loadw4(uint* arr, const float* rowk) {
    float4 a = ((const float4*)rowk)[0];
    float4 b = ((const float4*)rowk)[1];
    arr[0] = packh2(a.x, a.y);
    arr[1] = packh2(a.z, a.w);
    arr[2] = packh2(b.x, b.y);
    arr[3] = packh2(b.z, b.w);
}

// 3-step reduce-scatter (8 batches) + final butterfly over lane bit 2.
// Exit: a[0] = total for bl=(lane>>3)&7, o=lane&3 (duplicated across bit2).
__device__ __forceinline__ void rscat8(float (&a)[8], bool h32, bool h16, bool h8) {
#pragma unroll
    for (int j = 0; j < 4; j++) {
        float snd = h32 ? a[j] : a[j + 4];
        float kp  = h32 ? a[j + 4] : a[j];
        a[j] = kp + __shfl_xor(snd, 32, 64);
    }
#pragma unroll
    for (int j = 0; j < 2; j++) {
        float snd = h16 ? a[j] : a[j + 2];
        float kp  = h16 ? a[j + 2] : a[j];
        a[j] = kp + __shfl_xor(snd, 16, 64);
    }
    {
        float snd = h8 ? a[0] : a[1];
        float kp  = h8 ? a[1] : a[0];
        a[0] = kp + __shfl_xor(snd, 8, 64);
    }
    a[0] += __shfl_xor(a[0], 4, 64);
}

__global__ __launch_bounds__(NT) void enc_kernel(
    const float* __restrict__ dep, const float* __restrict__ ne,
    const float* __restrict__ gate_w, const float* __restrict__ gate_b,
    const float* __restrict__ map_w, const float* __restrict__ map_b,
    const float* __restrict__ w_ih, const float* __restrict__ w_hh,
    const float* __restrict__ b_ih, const float* __restrict__ b_hh,
    int* __restrict__ flags, uint* __restrict__ hv_ex, uint* __restrict__ hin_ex,
    float* __restrict__ out)
{
    // ~66 KiB LDS
    __shared__ __align__(16) uint shm[16512];
    uint*  hvS   = shm;                       // [8][512] staged group h
    float* GM    = (float*)(shm + 4096);      // [2][16*4][65] G,M rows (padded)
    float* red   = (float*)(shm + 12416);     // [3][512] cross-wave partials
    float* hbuf  = (float*)(shm + 13952);     // [64] h_in / hv per global (b,o)
    float* hbuf2 = (float*)(shm + 14016);     // [64] scan partial (s != t-1)
    float* gibuf = (float*)(shm + 14080);     // [3][64] gi per global (b,o)
    float* wihb  = (float*)(shm + 14272);     // [3][4][16] w_ih slice
    uint*  depb  = shm + 14464;               // [16][64][2] mask bits

    const int tid  = threadIdx.x;
    const int bid  = blockIdx.x;
    const int o0   = bid * 4;
    const int w    = tid >> 6;
    const int lane = tid & 63;
    const bool h32 = (lane & 32) != 0, h16 = (lane & 16) != 0, h8 = (lane & 8) != 0;
    const int olw  = lane & 3;
    const int kseg = w * 16 + (lane >> 2);
    const int k0   = kseg * 8;

    // ---- weights -> 20 VGPRs/lane ----
    uint wG[4], wM[4], wR[4], wZ[4], wN[4];
    loadw4(wG, gate_w + (o0 + olw) * 1024 + k0);
    loadw4(wM, map_w + (o0 + olw) * 1024 + k0);
    loadw4(wR, w_hh + (o0 + olw) * 1024 + k0);
    loadw4(wZ, w_hh + (1024 + o0 + olw) * 1024 + k0);
    loadw4(wN, w_hh + (2048 + o0 + olw) * 1024 + k0);

    // ---- LDS tables ----
#pragma unroll
    for (int e = 0; e < 4; e++) {
        int idx = tid + e * 512;
        int b = idx >> 7, tt = (idx >> 1) & 63, hf = idx & 1;
        const float4* dp = (const float4*)(dep + ((b * 64 + tt) * 64) + hf * 32);
        uint bits = 0;
#pragma unroll
        for (int s4 = 0; s4 < 8; s4++) {
            float4 v = dp[s4];
            bits |= (v.x != 0.0f) ? (1u << (s4 * 4 + 0)) : 0u;
            bits |= (v.y != 0.0f) ? (1u << (s4 * 4 + 1)) : 0u;
            bits |= (v.z != 0.0f) ? (1u << (s4 * 4 + 2)) : 0u;
            bits |= (v.w != 0.0f) ? (1u << (s4 * 4 + 3)) : 0u;
        }
        depb[idx] = bits;
    }
    if (tid < 192) {
        int g = tid >> 6, ol = (tid >> 4) & 3, c = tid & 15;
        wihb[tid] = w_ih[(g * 1024 + o0 + ol) * 16 + c];
    }

    // ---- hoisted per-thread scalars ----
    const int prS = tid >> 3;                // scan pair [0,64), global b
    const int bS = prS >> 2, olS = prS & 3, soct = tid & 7;
    const float gbS = gate_b[o0 + olS];
    const float mbS = map_b[o0 + olS];
    const float baseS = sigm(gbS) * mbS;
    // tail roles (tid<32): o depends only on tid&3 -> group-independent biases
    const int olQ = tid & 3, oQ = o0 + olQ, blQ = tid >> 2;
    const float gbQ = gate_b[oQ], mbQ = map_b[oQ];
    const float basQ = sigm(gbQ) * mbQ;
    const float bir = b_ih[oQ], biz = b_ih[1024 + oQ], bin_ = b_ih[2048 + oQ];
    const float bhr = b_hh[oQ], bhz = b_hh[1024 + oQ], bhn = b_hh[2048 + oQ];
    __syncthreads();

    int* fgA[2] = { flags, flags + 256 };

    for (int t = 0; t < 64; t++) {
        // ===== pre-poll work (no sync deps): gi for all 16 b, scan both groups =====
        if (tid < 64) {
            int bg = tid >> 2;
            const float* xr = ne + (bg * 64 + t) * 16;
            float4 xa = ((const float4*)xr)[0];
            float4 xb = ((const float4*)xr)[1];
            float4 xc = ((const float4*)xr)[2];
            float4 xd = ((const float4*)xr)[3];
#pragma unroll
            for (int g3 = 0; g3 < 3; g3++) {
                const float4* wp = (const float4*)&wihb[(g3 * 4 + olQ) * 16];
                float4 a0 = wp[0], a1 = wp[1], a2 = wp[2], a3 = wp[3];
                gibuf[g3 * 64 + tid] =
                      a0.x*xa.x + a0.y*xa.y + a0.z*xa.z + a0.w*xa.w
                    + a1.x*xb.x + a1.y*xb.y + a1.z*xb.z + a1.w*xb.w
                    + a2.x*xc.x + a2.y*xc.y + a2.z*xc.z + a2.w*xc.w
                    + a3.x*xd.x + a3.y*xd.y + a3.z*xd.z + a3.w*xd.w;
            }
        }
        {   // masked scan over s != t-1 (stable GM rows), both groups
            uint bl = depb[bS * 128 + t * 2 + (soct >> 2)];
            uint bits8 = (bl >> ((soct & 3) * 8)) & 0xFFu;
            int s0 = soct * 8;
            const float* Gp = GM + prS * 65;
            const float* Mp = GM + 4160 + prS * 65;
            float part = 0.0f;
#pragma unroll
            for (int j = 0; j < 8; j++) {
                int s = s0 + j;
                float Gv = Gp[s], Mv = Mp[s];
                float term = ((bits8 >> j) & 1u) ? (sigm(Gv + gbS) * (Mv + mbS)) : baseS;
                part += (s == t - 1) ? 0.0f : term;
            }
            part += __shfl_xor(part, 1, 64);
            part += __shfl_xor(part, 2, 64);
            part += __shfl_xor(part, 4, 64);
            if (soct == 0) hbuf2[prS] = part;
        }
        __syncthreads();

        // ===== phase A per group =====
#pragma unroll
        for (int g = 0; g < 2; g++) {
            int*  fg   = fgA[g];
            uint* hvx  = hv_ex  + g * 4096;
            uint* hinx = hin_ex + g * 4096;
            if (t > 0) {
                wait_flags(fg, 2 * t);
                stage2(hvx, hvS, tid);
                __syncthreads();
                float aG[8], aM[8];
#pragma unroll
                for (int b = 0; b < 8; b++) { aG[b] = 0.0f; aM[b] = 0.0f; }
#pragma unroll
                for (int b = 0; b < 8; b++) {
                    uint4v hq = *(const uint4v*)&hvS[b * 512 + kseg * 4];
#pragma unroll
                    for (int q = 0; q < 4; q++) {
                        aG[b] = fdot2(wG[q], hq[q], aG[b]);
                        aM[b] = fdot2(wM[q], hq[q], aM[b]);
                    }
                }
                rscat8(aG, h32, h16, h8);
                rscat8(aM, h32, h16, h8);
                red[w * 64 + lane]       = aG[0];
                red[512 + w * 64 + lane] = aM[0];
                __syncthreads();
                if (tid < 32) {
                    int rl = (blQ << 3) | olQ;
                    float nG = 0.0f, nM = 0.0f;
#pragma unroll
                    for (int ww = 0; ww < 8; ww++) {
                        nG += red[ww * 64 + rl];
                        nM += red[512 + ww * 64 + rl];
                    }
                    int pair = g * 32 + tid;
                    GM[pair * 65 + (t - 1)] = nG;
                    GM[4160 + pair * 65 + (t - 1)] = nM;
                    uint blb = depb[(g * 8 + blQ) * 128 + t * 2 + ((t - 1) >> 5)];
                    int bit = (blb >> ((t - 1) & 31)) & 1;
                    float term = bit ? (sigm(nG + gbQ) * (nM + mbQ)) : basQ;
                    hbuf[pair] = hbuf2[pair] + term;
                }
            } else {
                if (tid < 32) hbuf[g * 32 + tid] = hbuf2[g * 32 + tid];
            }
            // wave-0 program order: tid<8 publish after tid<32 writes (same wave);
            // per-wave vmcnt(0) in st_dev2_wait acks ALL publish lanes before flag.
            if (tid < 8) {
                uint p0 = packh2(hbuf[g * 32 + tid * 4 + 0], hbuf[g * 32 + tid * 4 + 1]);
                uint p1 = packh2(hbuf[g * 32 + tid * 4 + 2], hbuf[g * 32 + tid * 4 + 3]);
                st_dev2_wait(hinx + tid * 512 + bid * 2, p0, p1);
            }
            if (tid == 0) st_flag_noack(fg + bid, 2 * t + 1);
        }

        // ===== phase B per group =====
#pragma unroll
        for (int g = 0; g < 2; g++) {
            int*  fg   = fgA[g];
            uint* hvx  = hv_ex  + g * 4096;
            uint* hinx = hin_ex + g * 4096;
            wait_flags(fg, 2 * t + 1);
            stage2(hinx, hvS, tid);
            __syncthreads();
            float aR[8], aZ[8], aN[8];
#pragma unroll
            for (int b = 0; b < 8; b++) { aR[b] = 0.0f; aZ[b] = 0.0f; aN[b] = 0.0f; }
#pragma unroll
            for (int b = 0; b < 8; b++) {
                uint4v hq = *(const uint4v*)&hvS[b * 512 + kseg * 4];
#pragma unroll
                for (int q = 0; q < 4; q++) {
                    aR[b] = fdot2(wR[q], hq[q], aR[b]);
                    aZ[b] = fdot2(wZ[q], hq[q], aZ[b]);
                    aN[b] = fdot2(wN[q], hq[q], aN[b]);
                }
            }
            rscat8(aR, h32, h16, h8);
            rscat8(aZ, h32, h16, h8);
            rscat8(aN, h32, h16, h8);
            red[w * 64 + lane]        = aR[0];
            red[512 + w * 64 + lane]  = aZ[0];
            red[1024 + w * 64 + lane] = aN[0];
            __syncthreads();
            if (tid < 32) {
                int rl = (blQ << 3) | olQ;
                float ghr = 0.0f, ghz = 0.0f, ghn = 0.0f;
#pragma unroll
                for (int ww = 0; ww < 8; ww++) {
                    ghr += red[ww * 64 + rl];
                    ghz += red[512 + ww * 64 + rl];
                    ghn += red[1024 + ww * 64 + rl];
                }
                int pair = g * 32 + tid;
                float h_in = hbuf[pair];
                float r = sigm(gibuf[pair] + bir + ghr + bhr);
                float z = sigm(gibuf[64 + pair] + biz + ghz + bhz);
                float n = tanhfast(gibuf[128 + pair] + bin_ + r * (ghn + bhn));
                float hv = (1.0f - z) * n + z * h_in;
                if (t == 63) out[(g * 8 + blQ) * 1024 + oQ] = hv;
                hbuf[pair] = hv;
            }
            if (t < 63) {
                if (tid < 8) {
                    uint p0 = packh2(hbuf[g * 32 + tid * 4 + 0], hbuf[g * 32 + tid * 4 + 1]);
                    uint p1 = packh2(hbuf[g * 32 + tid * 4 + 2], hbuf[g * 32 + tid * 4 + 3]);
                    st_dev2_wait(hvx + tid * 512 + bid * 2, p0, p1);
                }
                if (tid == 0) st_flag_noack(fg + bid, 2 * t + 2);
            }
        }
    }
    // mu/logvar computed by kF (separate dispatch) from the f32 hv in out.
}

__device__ __forceinline__ float wave_sum(float v) {
    v += __shfl_xor(v, 32, 64);
    v += __shfl_xor(v, 16, 64);
    v += __shfl_xor(v, 8, 64);
    v += __shfl_xor(v, 4, 64);
    v += __shfl_xor(v, 2, 64);
    v += __shfl_xor(v, 1, 64);
    return v;
}

// mu/logvar: out[16K..32K) = hv @ l1w^T + b1, out[32K..48K) = hv @ l2w^T + b2.
__global__ __launch_bounds__(256) void kF(
    float* out, const float* __restrict__ w1, const float* __restrict__ b1,
    const float* __restrict__ w2, const float* __restrict__ b2)
{
    const int wid = threadIdx.x >> 6;
    const int kl = threadIdx.x & 63;
    const int o = blockIdx.x * 2 + (wid >> 1);
    const int b0 = (wid & 1) * 8;

    float w1v[16], w2v[16];
#pragma unroll
    for (int i = 0; i < 16; i++) {
        w1v[i] = w1[o * 1024 + kl + 64 * i];
        w2v[i] = w2[o * 1024 + kl + 64 * i];
    }
    for (int b = b0; b < b0 + 8; b++) {
        float p1 = 0.0f, p2 = 0.0f;
#pragma unroll
        for (int i = 0; i < 16; i++) {
            float h = out[b * 1024 + kl + 64 * i];
            p1 += h * w1v[i];
            p2 += h * w2v[i];
        }
        p1 = wave_sum(p1);
        p2 = wave_sum(p2);
        if (kl == 0) {
            out[16384 + b * 1024 + o] = p1 + b1[o];
            out[32768 + b * 1024 + o] = p2 + b2[o];
        }
    }
}

extern "C" void kernel_launch(void* const* d_in, const int* in_sizes, int n_in,
                              void* d_out, int out_size, void* d_ws, size_t ws_size,
                              hipStream_t stream) {
    const float* dep     = (const float*)d_in[0];
    const float* ne      = (const float*)d_in[1];
    const float* gate_w  = (const float*)d_in[2];
    const float* gate_b  = (const float*)d_in[3];
    const float* map_w   = (const float*)d_in[4];
    const float* map_b   = (const float*)d_in[5];
    const float* w_ih    = (const float*)d_in[6];
    const float* w_hh    = (const float*)d_in[7];
    const float* b_ih    = (const float*)d_in[8];
    const float* b_hh    = (const float*)d_in[9];
    const float* lin11_w = (const float*)d_in[10];
    const float* lin11_b = (const float*)d_in[11];
    const float* lin12_w = (const float*)d_in[12];
    const float* lin12_b = (const float*)d_in[13];

    int* wsI = (int*)d_ws;
    int* flags   = wsI;                      // [2][256] ints
    uint* hv_ex  = (uint*)(wsI + 512);       // [2][8][512] uints
    uint* hin_ex = hv_ex + 8192;             // [2][8][512] uints
    float* outp  = (float*)d_out;

    hipMemsetAsync((void*)flags, 0, 512 * 4, stream);

    void* args[] = {
        (void*)&dep, (void*)&ne, (void*)&gate_w, (void*)&gate_b,
        (void*)&map_w, (void*)&map_b, (void*)&w_ih, (void*)&w_hh,
        (void*)&b_ih, (void*)&b_hh,
        (void*)&flags, (void*)&hv_ex, (void*)&hin_ex, (void*)&outp,
    };
    hipError_t e = hipLaunchCooperativeKernel((void*)enc_kernel, dim3(NBLK), dim3(NT),
                                              args, 0, stream);
    if (e != hipSuccess) {
        enc_kernel<<<dim3(NBLK), dim3(NT), 0, stream>>>(
            dep, ne, gate_w, gate_b, map_w, map_b, w_ih, w_hh, b_ih, b_hh,
            flags, hv_ex, hin_ex, outp);
    }
    kF<<<dim3(512), dim3(256), 0, stream>>>(outp, lin11_w, lin11_b, lin12_w, lin12_b);
}

// Round 13
// 637.175 us; speedup vs baseline: 1.1340x; 1.1340x over previous
//
#include <hip/hip_runtime.h>

// DAG-GRU encoder v4: self-flagging data exchange (r11 structure, 1-RTT sync).
// B=16, S=64, H=1024, C=16. 256 blocks x 512 thr; block = 4-o tile x 16 b.
// Weights 20 VGPR/lane (zero replication, no spill). Exchange uints carry the
// step parity in bit0 (one fp16 mantissa LSB): consumers poll their own staged
// chunks until tags match -> no flags, no publish-ack, no separate stage RTT.
// Replay safety: launch memsets exchange to 0xFF (tag 1); first writes tag 0.
// ABA-safe within a run by the two-phase handshake (hv(t) written only after
// all blocks consumed h_in(t), which required consuming hv(t-1)).
// kF: separate kernel computes mu/logvar from validated f32 hv in out.

#define NT 512
#define NBLK 256

typedef unsigned int uint;
typedef __attribute__((ext_vector_type(2))) _Float16 half2v;
typedef __attribute__((ext_vector_type(2))) uint uint2v;
typedef __attribute__((ext_vector_type(4))) uint uint4v;

__device__ __forceinline__ float fdot2(uint w, uint h, float acc) {
#if __has_builtin(__builtin_amdgcn_fdot2)
    return __builtin_amdgcn_fdot2(__builtin_bit_cast(half2v, w),
                                  __builtin_bit_cast(half2v, h), acc, false);
#else
    half2v a = __builtin_bit_cast(half2v, w);
    half2v b = __builtin_bit_cast(half2v, h);
    return acc + (float)a[0] * (float)b[0] + (float)a[1] * (float)b[1];
#endif
}

__device__ __forceinline__ uint packh2(float a, float b) {
    half2v h; h[0] = (_Float16)a; h[1] = (_Float16)b;
    return __builtin_bit_cast(uint, h);
}

__device__ __forceinline__ float sigm(float x) { return 1.0f / (1.0f + __expf(-x)); }
__device__ __forceinline__ float tanhfast(float x) { return 2.0f / (1.0f + __expf(-2.0f * x)) - 1.0f; }

// poll-stage: load own 4 chunks (64B) until ALL 16 uints carry tag `want`,
// then write to LDS. The poll IS the stage (data self-flagging via bit0).
__device__ __forceinline__ void pollstage4(const uint* src, uint* lds, int tid, uint want) {
    const uint* a0 = src + tid * 4;
    const uint* a1 = a0 + 2048;
    const uint* a2 = a0 + 4096;
    const uint* a3 = a0 + 6144;
    uint4v u0, u1, u2, u3;
    for (;;) {
        asm volatile("global_load_dwordx4 %0, %4, off sc0 sc1\n\t"
                     "global_load_dwordx4 %1, %5, off sc0 sc1\n\t"
                     "global_load_dwordx4 %2, %6, off sc0 sc1\n\t"
                     "global_load_dwordx4 %3, %7, off sc0 sc1\n\t"
                     "s_waitcnt vmcnt(0)"
                     : "=&v"(u0), "=&v"(u1), "=&v"(u2), "=&v"(u3)
                     : "v"(a0), "v"(a1), "v"(a2), "v"(a3) : "memory");
        uint andv = u0[0] & u0[1] & u0[2] & u0[3] & u1[0] & u1[1] & u1[2] & u1[3]
                  & u2[0] & u2[1] & u2[2] & u2[3] & u3[0] & u3[1] & u3[2] & u3[3];
        uint orv  = u0[0] | u0[1] | u0[2] | u0[3] | u1[0] | u1[1] | u1[2] | u1[3]
                  | u2[0] | u2[1] | u2[2] | u2[3] | u3[0] | u3[1] | u3[2] | u3[3];
        if (want ? ((andv & 1u) != 0u) : ((orv & 1u) == 0u)) break;
    }
    *(uint4v*)(lds + tid * 4)        = u0;
    *(uint4v*)(lds + tid * 4 + 2048) = u1;
    *(uint4v*)(lds + tid * 4 + 4096) = u2;
    *(uint4v*)(lds + tid * 4 + 6144) = u3;
}

// fire-and-forget tagged publish (2 uints, bit0 = tag on each)
__device__ __forceinline__ void st_pub2(uint* p, uint lo, uint hi, uint tag) {
    uint2v v;
    v[0] = (lo & ~1u) | tag;
    v[1] = (hi & ~1u) | tag;
    asm volatile("global_store_dwordx2 %0, %1, off sc0 sc1" :: "v"(p), "v"(v) : "memory");
}

__device__ __forceinline__ void loadw4(uint* arr, const float* rowk) {
    float4 a = ((const float4*)rowk)[0];
    float4 b = ((const float4*)rowk)[1];
    arr[0] = packh2(a.x, a.y);
    arr[1] = packh2(a.z, a.w);
    arr[2] = packh2(b.x, b.y);
    arr[3] = packh2(b.z, b.w);
}

// 4-step reduce-scatter over lane bits 5..2 (k-dim). Exit: a[0] = total for
// b = (lane>>2)&15, o = lane&3.
__device__ __forceinline__ void rscat16(float (&a)[16], bool h32, bool h16, bool h8, bool h4b) {
#pragma unroll
    for (int j = 0; j < 8; j++) {
        float snd = h32 ? a[j] : a[j + 8];
        float kp  = h32 ? a[j + 8] : a[j];
        a[j] = kp + __shfl_xor(snd, 32, 64);
    }
#pragma unroll
    for (int j = 0; j < 4; j++) {
        float snd = h16 ? a[j] : a[j + 4];
        float kp  = h16 ? a[j + 4] : a[j];
        a[j] = kp + __shfl_xor(snd, 16, 64);
    }
#pragma unroll
    for (int j = 0; j < 2; j++) {
        float snd = h8 ? a[j] : a[j + 2];
        float kp  = h8 ? a[j + 2] : a[j];
        a[j] = kp + __shfl_xor(snd, 8, 64);
    }
    {
        float snd = h4b ? a[0] : a[1];
        float kp  = h4b ? a[1] : a[0];
        a[0] = kp + __shfl_xor(snd, 4, 64);
    }
}

__global__ __launch_bounds__(NT) void enc_kernel(
    const float* __restrict__ dep, const float* __restrict__ ne,
    const float* __restrict__ gate_w, const float* __restrict__ gate_b,
    const float* __restrict__ map_w, const float* __restrict__ map_b,
    const float* __restrict__ w_ih, const float* __restrict__ w_hh,
    const float* __restrict__ b_ih, const float* __restrict__ b_hh,
    uint* __restrict__ hv_ex, uint* __restrict__ hin_ex,
    float* __restrict__ out)
{
    // ~80 KiB LDS -> 1 block/CU
    __shared__ __align__(16) uint shm[20416];
    uint*  hvS   = shm;                       // [16][512] staged h (fp16 pairs)
    float* GM    = (float*)(shm + 8192);      // [2][16*4][65]: G,M rows (padded)
    float* red   = (float*)(shm + 16512);     // [3][512] cross-wave partials
    float* hbuf  = (float*)(shm + 18048);     // [64] h_in / hv per (b,o)
    float* hbuf2 = (float*)(shm + 18112);     // [64] scan partial (s != t-1)
    float* wihb  = (float*)(shm + 18176);     // [3][4][16] w_ih slice
    uint*  depb  = shm + 18368;               // [16][64][2] mask bits

    const int tid  = threadIdx.x;
    const int bid  = blockIdx.x;
    const int o0   = bid * 4;
    const int w    = tid >> 6;
    const int lane = tid & 63;
    const bool h32 = (lane & 32) != 0, h16 = (lane & 16) != 0;
    const bool h8  = (lane & 8) != 0,  h4b = (lane & 4) != 0;
    const int olw  = lane & 3;
    const int kseg = w * 16 + (lane >> 2);
    const int k0   = kseg * 8;

    // ---- weights -> 20 VGPRs/lane (unique slice, zero replication) ----
    uint wG[4], wM[4], wR[4], wZ[4], wN[4];
    loadw4(wG, gate_w + (o0 + olw) * 1024 + k0);
    loadw4(wM, map_w + (o0 + olw) * 1024 + k0);
    loadw4(wR, w_hh + (o0 + olw) * 1024 + k0);
    loadw4(wZ, w_hh + (1024 + o0 + olw) * 1024 + k0);
    loadw4(wN, w_hh + (2048 + o0 + olw) * 1024 + k0);

    // ---- LDS tables: dep bits (all 16 b), w_ih slice ----
#pragma unroll
    for (int e = 0; e < 4; e++) {
        int idx = tid + e * 512;
        int b = idx >> 7, tt = (idx >> 1) & 63, hf = idx & 1;
        const float4* dp = (const float4*)(dep + ((b * 64 + tt) * 64) + hf * 32);
        uint bits = 0;
#pragma unroll
        for (int s4 = 0; s4 < 8; s4++) {
            float4 v = dp[s4];
            bits |= (v.x != 0.0f) ? (1u << (s4 * 4 + 0)) : 0u;
            bits |= (v.y != 0.0f) ? (1u << (s4 * 4 + 1)) : 0u;
            bits |= (v.z != 0.0f) ? (1u << (s4 * 4 + 2)) : 0u;
            bits |= (v.w != 0.0f) ? (1u << (s4 * 4 + 3)) : 0u;
        }
        depb[idx] = bits;
    }
    if (tid < 192) {
        int g = tid >> 6, ol = (tid >> 4) & 3, c = tid & 15;
        wihb[tid] = w_ih[(g * 1024 + o0 + ol) * 16 + c];
    }

    // ---- hoisted per-thread scalars ----
    const int prS = tid >> 3;                // scan pair [0,64)
    const int bS = prS >> 2, olS = prS & 3, soct = tid & 7;
    const float gbS = gate_b[o0 + olS];
    const float mbS = map_b[o0 + olS];
    const float baseS = sigm(gbS) * mbS;
    const int bP = tid >> 2, olP = tid & 3, oP = o0 + olP;  // tid<64 roles
    const float gbP = gate_b[oP], mbP = map_b[oP];
    const float basP = sigm(gbP) * mbP;
    const float bir = b_ih[oP], biz = b_ih[1024 + oP], bin_ = b_ih[2048 + oP];
    const float bhr = b_hh[oP], bhz = b_hh[1024 + oP], bhn = b_hh[2048 + oP];
    __syncthreads();

    for (int t = 0; t < 64; t++) {
        const uint tagT = (uint)(t & 1);
        // ===== phase A pre-work: masked scan over s != t-1 (stable GM rows) =====
        {
            uint bl = depb[bS * 128 + t * 2 + (soct >> 2)];
            uint bits8 = (bl >> ((soct & 3) * 8)) & 0xFFu;
            int s0 = soct * 8;
            const float* Gp = GM + prS * 65;
            const float* Mp = GM + 4160 + prS * 65;
            float part = 0.0f;
#pragma unroll
            for (int j = 0; j < 8; j++) {
                int s = s0 + j;
                float Gv = Gp[s], Mv = Mp[s];
                float term = ((bits8 >> j) & 1u) ? (sigm(Gv + gbS) * (Mv + mbS)) : baseS;
                part += (s == t - 1) ? 0.0f : term;
            }
            part += __shfl_xor(part, 1, 64);
            part += __shfl_xor(part, 2, 64);
            part += __shfl_xor(part, 4, 64);
            if (soct == 0) hbuf2[prS] = part;
        }

        // ===== phase A: poll-stage hv(t-1), GEMV, finish h_in =====
        if (t > 0) {
            pollstage4(hv_ex, hvS, tid, tagT ^ 1u);   // hv(t-1) tag = (t-1)&1
            __syncthreads();
            float aG[16], aM[16];
#pragma unroll
            for (int b = 0; b < 16; b++) { aG[b] = 0.0f; aM[b] = 0.0f; }
#pragma unroll
            for (int b = 0; b < 16; b++) {
                uint4v hq = *(const uint4v*)&hvS[b * 512 + kseg * 4];
#pragma unroll
                for (int q = 0; q < 4; q++) {
                    aG[b] = fdot2(wG[q], hq[q], aG[b]);
                    aM[b] = fdot2(wM[q], hq[q], aM[b]);
                }
            }
            rscat16(aG, h32, h16, h8, h4b);
            rscat16(aM, h32, h16, h8, h4b);
            red[w * 64 + lane]       = aG[0];
            red[512 + w * 64 + lane] = aM[0];
            __syncthreads();
            if (tid < 64) {
                float nG = 0.0f, nM = 0.0f;
#pragma unroll
                for (int ww = 0; ww < 8; ww++) {
                    nG += red[ww * 64 + tid];
                    nM += red[512 + ww * 64 + tid];
                }
                GM[tid * 65 + (t - 1)] = nG;
                GM[4160 + tid * 65 + (t - 1)] = nM;
                uint blb = depb[bP * 128 + t * 2 + ((t - 1) >> 5)];
                int bit = (blb >> ((t - 1) & 31)) & 1;
                float term = bit ? (sigm(nG + gbP) * (nM + mbP)) : basP;
                hbuf[tid] = hbuf2[tid] + term;
            }
        } else {
            __syncthreads();
            if (tid < 64) hbuf[tid] = hbuf2[tid];
        }
        __syncthreads();
        if (tid < 16) {   // publish h_in slice, fire-and-forget, tag = t&1
            uint p0 = packh2(hbuf[tid * 4 + 0], hbuf[tid * 4 + 1]);
            uint p1 = packh2(hbuf[tid * 4 + 2], hbuf[tid * 4 + 3]);
            st_pub2(hin_ex + tid * 512 + bid * 2, p0, p1, tagT);
        }

        // ===== phase B: gi (covers store flight), poll-stage h_in, GEMV, GRU =====
        float gi0 = 0.0f, gi1 = 0.0f, gi2 = 0.0f;
        if (tid < 64) {
            const float* xr = ne + (bP * 64 + t) * 16;
            float4 xa = ((const float4*)xr)[0];
            float4 xb = ((const float4*)xr)[1];
            float4 xc = ((const float4*)xr)[2];
            float4 xd = ((const float4*)xr)[3];
            const float4* w0p = (const float4*)&wihb[olP * 16];
            const float4* w1p = (const float4*)&wihb[64 + olP * 16];
            const float4* w2p = (const float4*)&wihb[128 + olP * 16];
            float4 a0 = w0p[0], a1 = w0p[1], a2 = w0p[2], a3 = w0p[3];
            gi0 = a0.x*xa.x + a0.y*xa.y + a0.z*xa.z + a0.w*xa.w
                + a1.x*xb.x + a1.y*xb.y + a1.z*xb.z + a1.w*xb.w
                + a2.x*xc.x + a2.y*xc.y + a2.z*xc.z + a2.w*xc.w
                + a3.x*xd.x + a3.y*xd.y + a3.z*xd.z + a3.w*xd.w;
            float4 b0 = w1p[0], b1 = w1p[1], b2 = w1p[2], b3 = w1p[3];
            gi1 = b0.x*xa.x + b0.y*xa.y + b0.z*xa.z + b0.w*xa.w
                + b1.x*xb.x + b1.y*xb.y + b1.z*xb.z + b1.w*xb.w
                + b2.x*xc.x + b2.y*xc.y + b2.z*xc.z + b2.w*xc.w
                + b3.x*xd.x + b3.y*xd.y + b3.z*xd.z + b3.w*xd.w;
            float4 c0 = w2p[0], c1 = w2p[1], c2 = w2p[2], c3 = w2p[3];
            gi2 = c0.x*xa.x + c0.y*xa.y + c0.z*xa.z + c0.w*xa.w
                + c1.x*xb.x + c1.y*xb.y + c1.z*xb.z + c1.w*xb.w
                + c2.x*xc.x + c2.y*xc.y + c2.z*xc.z + c2.w*xc.w
                + c3.x*xd.x + c3.y*xd.y + c3.z*xd.z + c3.w*xd.w;
        }
        pollstage4(hin_ex, hvS, tid, tagT);   // h_in(t) tag = t&1
        __syncthreads();
        float aR[16], aZ[16], aN[16];
#pragma unroll
        for (int b = 0; b < 16; b++) { aR[b] = 0.0f; aZ[b] = 0.0f; aN[b] = 0.0f; }
#pragma unroll
        for (int b = 0; b < 16; b++) {
            uint4v hq = *(const uint4v*)&hvS[b * 512 + kseg * 4];
#pragma unroll
            for (int q = 0; q < 4; q++) {
                aR[b] = fdot2(wR[q], hq[q], aR[b]);
                aZ[b] = fdot2(wZ[q], hq[q], aZ[b]);
                aN[b] = fdot2(wN[q], hq[q], aN[b]);
            }
        }
        rscat16(aR, h32, h16, h8, h4b);
        rscat16(aZ, h32, h16, h8, h4b);
        rscat16(aN, h32, h16, h8, h4b);
        red[w * 64 + lane]        = aR[0];
        red[512 + w * 64 + lane]  = aZ[0];
        red[1024 + w * 64 + lane] = aN[0];
        __syncthreads();
        if (tid < 64) {
            float ghr = 0.0f, ghz = 0.0f, ghn = 0.0f;
#pragma unroll
            for (int ww = 0; ww < 8; ww++) {
                ghr += red[ww * 64 + tid];
                ghz += red[512 + ww * 64 + tid];
                ghn += red[1024 + ww * 64 + tid];
            }
            float h_in = hbuf[tid];
            float r = sigm(gi0 + bir + ghr + bhr);
            float z = sigm(gi1 + biz + ghz + bhz);
            float n = tanhfast(gi2 + bin_ + r * (ghn + bhn));
            float hv = (1.0f - z) * n + z * h_in;
            if (t == 63) out[bP * 1024 + oP] = hv;
            hbuf[tid] = hv;
        }
        __syncthreads();
        if (t < 63 && tid < 16) {   // publish hv slice, tag = t&1
            uint p0 = packh2(hbuf[tid * 4 + 0], hbuf[tid * 4 + 1]);
            uint p1 = packh2(hbuf[tid * 4 + 2], hbuf[tid * 4 + 3]);
            st_pub2(hv_ex + tid * 512 + bid * 2, p0, p1, tagT);
        }
    }
    // mu/logvar computed by kF (separate dispatch) from the f32 hv in out.
}

__device__ __forceinline__ float wave_sum(float v) {
    v += __shfl_xor(v, 32, 64);
    v += __shfl_xor(v, 16, 64);
    v += __shfl_xor(v, 8, 64);
    v += __shfl_xor(v, 4, 64);
    v += __shfl_xor(v, 2, 64);
    v += __shfl_xor(v, 1, 64);
    return v;
}

// mu/logvar: out[16K..32K) = hv @ l1w^T + b1, out[32K..48K) = hv @ l2w^T + b2.
__global__ __launch_bounds__(256) void kF(
    float* out, const float* __restrict__ w1, const float* __restrict__ b1,
    const float* __restrict__ w2, const float* __restrict__ b2)
{
    const int wid = threadIdx.x >> 6;
    const int kl = threadIdx.x & 63;
    const int o = blockIdx.x * 2 + (wid >> 1);
    const int b0 = (wid & 1) * 8;

    float w1v[16], w2v[16];
#pragma unroll
    for (int i = 0; i < 16; i++) {
        w1v[i] = w1[o * 1024 + kl + 64 * i];
        w2v[i] = w2[o * 1024 + kl + 64 * i];
    }
    for (int b = b0; b < b0 + 8; b++) {
        float p1 = 0.0f, p2 = 0.0f;
#pragma unroll
        for (int i = 0; i < 16; i++) {
            float h = out[b * 1024 + kl + 64 * i];
            p1 += h * w1v[i];
            p2 += h * w2v[i];
        }
        p1 = wave_sum(p1);
        p2 = wave_sum(p2);
        if (kl == 0) {
            out[16384 + b * 1024 + o] = p1 + b1[o];
            out[32768 + b * 1024 + o] = p2 + b2[o];
        }
    }
}

extern "C" void kernel_launch(void* const* d_in, const int* in_sizes, int n_in,
                              void* d_out, int out_size, void* d_ws, size_t ws_size,
                              hipStream_t stream) {
    const float* dep     = (const float*)d_in[0];
    const float* ne      = (const float*)d_in[1];
    const float* gate_w  = (const float*)d_in[2];
    const float* gate_b  = (const float*)d_in[3];
    const float* map_w   = (const float*)d_in[4];
    const float* map_b   = (const float*)d_in[5];
    const float* w_ih    = (const float*)d_in[6];
    const float* w_hh    = (const float*)d_in[7];
    const float* b_ih    = (const float*)d_in[8];
    const float* b_hh    = (const float*)d_in[9];
    const float* lin11_w = (const float*)d_in[10];
    const float* lin11_b = (const float*)d_in[11];
    const float* lin12_w = (const float*)d_in[12];
    const float* lin12_b = (const float*)d_in[13];

    uint* hv_ex  = (uint*)d_ws;              // [16][512] uints
    uint* hin_ex = hv_ex + 8192;             // [16][512] uints
    float* outp  = (float*)d_out;

    // tag-reset: all exchange uints -> LSB=1 (first real publishes use tag 0)
    hipMemsetAsync((void*)hv_ex, 0xFF, 2 * 8192 * 4, stream);

    void* args[] = {
        (void*)&dep, (void*)&ne, (void*)&gate_w, (void*)&gate_b,
        (void*)&map_w, (void*)&map_b, (void*)&w_ih, (void*)&w_hh,
        (void*)&b_ih, (void*)&b_hh,
        (void*)&hv_ex, (void*)&hin_ex, (void*)&outp,
    };
    hipError_t e = hipLaunchCooperativeKernel((void*)enc_kernel, dim3(NBLK), dim3(NT),
                                              args, 0, stream);
    if (e != hipSuccess) {
        enc_kernel<<<dim3(NBLK), dim3(NT), 0, stream>>>(
            dep, ne, gate_w, gate_b, map_w, map_b, w_ih, w_hh, b_ih, b_hh,
            hv_ex, hin_ex, outp);
    }
    kF<<<dim3(512), dim3(256), 0, stream>>>(outp, lin11_w, lin11_b, lin12_w, lin12_b);
}

// Round 14
// 526.921 us; speedup vs baseline: 1.3713x; 1.2092x over previous
//
#include <hip/hip_runtime.h>

// DAG-GRU encoder v5 = r11 structure + tagged fire-and-forget publishes.
// B=16, S=64, H=1024, C=16. 256 blocks x 512 thr; block = 4-o tile x 16 b.
// Weights 20 VGPR/lane (zero replication, no spill). Sync per phase:
//   producer: tagged data stores (bit0 = t&1, fire-and-forget) then flag
//             store (no data-ack -> one fewer IF RTT than r11);
//   consumer: poll 256 flags (cheap, 16B/lane) -> stage once -> verify tags
//             on staged regs -> respin only if flag overtook data (rare).
// Replay safety: exchange memset 0xFF (tag 1) per launch; first writes tag 0.
// ABA excluded by the two-phase handshake (hv(t+1) written only after all
// blocks consumed hv(t)). kF: separate kernel for mu/logvar from f32 hv.

#define NT 512
#define NBLK 256

typedef unsigned int uint;
typedef __attribute__((ext_vector_type(2))) _Float16 half2v;
typedef __attribute__((ext_vector_type(2))) uint uint2v;
typedef __attribute__((ext_vector_type(4))) uint uint4v;
typedef __attribute__((ext_vector_type(4))) int int4v;

__device__ __forceinline__ float fdot2(uint w, uint h, float acc) {
#if __has_builtin(__builtin_amdgcn_fdot2)
    return __builtin_amdgcn_fdot2(__builtin_bit_cast(half2v, w),
                                  __builtin_bit_cast(half2v, h), acc, false);
#else
    half2v a = __builtin_bit_cast(half2v, w);
    half2v b = __builtin_bit_cast(half2v, h);
    return acc + (float)a[0] * (float)b[0] + (float)a[1] * (float)b[1];
#endif
}

__device__ __forceinline__ uint packh2(float a, float b) {
    half2v h; h[0] = (_Float16)a; h[1] = (_Float16)b;
    return __builtin_bit_cast(uint, h);
}

__device__ __forceinline__ float sigm(float x) { return 1.0f / (1.0f + __expf(-x)); }
__device__ __forceinline__ float tanhfast(float x) { return 2.0f / (1.0f + __expf(-2.0f * x)) - 1.0f; }

// stage own 4 chunks (64B) -> verify per-uint tags -> respin if stale -> LDS
__device__ __forceinline__ void stagev4(const uint* src, uint* lds, int tid, uint want) {
    const uint* a0 = src + tid * 4;
    const uint* a1 = a0 + 2048;
    const uint* a2 = a0 + 4096;
    const uint* a3 = a0 + 6144;
    uint4v u0, u1, u2, u3;
    for (;;) {
        asm volatile("global_load_dwordx4 %0, %4, off sc0 sc1\n\t"
                     "global_load_dwordx4 %1, %5, off sc0 sc1\n\t"
                     "global_load_dwordx4 %2, %6, off sc0 sc1\n\t"
                     "global_load_dwordx4 %3, %7, off sc0 sc1\n\t"
                     "s_waitcnt vmcnt(0)"
                     : "=&v"(u0), "=&v"(u1), "=&v"(u2), "=&v"(u3)
                     : "v"(a0), "v"(a1), "v"(a2), "v"(a3) : "memory");
        uint andv = u0[0] & u0[1] & u0[2] & u0[3] & u1[0] & u1[1] & u1[2] & u1[3]
                  & u2[0] & u2[1] & u2[2] & u2[3] & u3[0] & u3[1] & u3[2] & u3[3];
        uint orv  = u0[0] | u0[1] | u0[2] | u0[3] | u1[0] | u1[1] | u1[2] | u1[3]
                  | u2[0] | u2[1] | u2[2] | u2[3] | u3[0] | u3[1] | u3[2] | u3[3];
        if (want ? ((andv & 1u) != 0u) : ((orv & 1u) == 0u)) break;
    }
    *(uint4v*)(lds + tid * 4)        = u0;
    *(uint4v*)(lds + tid * 4 + 2048) = u1;
    *(uint4v*)(lds + tid * 4 + 4096) = u2;
    *(uint4v*)(lds + tid * 4 + 6144) = u3;
}

// fire-and-forget tagged publish (2 uints, bit0 = tag on each)
__device__ __forceinline__ void st_pub2(uint* p, uint lo, uint hi, uint tag) {
    uint2v v;
    v[0] = (lo & ~1u) | tag;
    v[1] = (hi & ~1u) | tag;
    asm volatile("global_store_dwordx2 %0, %1, off sc0 sc1" :: "v"(p), "v"(v) : "memory");
}
__device__ __forceinline__ void st_flag_noack(int* p, int v) {
    asm volatile("global_store_dword %0, %1, off sc0 sc1" :: "v"(p), "v"(v) : "memory");
}

// poll all 256 single-writer flags (4 per lane of wave 0) until >= gen
__device__ __forceinline__ void wait_flags(const int* fl, int gen) {
    if (threadIdx.x < 64) {
        const int* pp = fl + threadIdx.x * 4;
        bool done;
        do {
            int4v v;
            asm volatile("global_load_dwordx4 %0, %1, off sc0 sc1\n\ts_waitcnt vmcnt(0)"
                         : "=v"(v) : "v"(pp) : "memory");
            done = __all(v[0] >= gen && v[1] >= gen && v[2] >= gen && v[3] >= gen);
        } while (!done);
    }
    __syncthreads();
}

__device__ __forceinline__ void loadw4(uint* arr, const float* rowk) {
    float4 a = ((const float4*)rowk)[0];
    float4 b = ((const float4*)rowk)[1];
    arr[0] = packh2(a.x, a.y);
    arr[1] = packh2(a.z, a.w);
    arr[2] = packh2(b.x, b.y);
    arr[3] = packh2(b.z, b.w);
}

// 4-step reduce-scatter over lane bits 5..2 (k-dim). Exit: a[0] = total for
// b = (lane>>2)&15, o = lane&3.
__device__ __forceinline__ void rscat16(float (&a)[16], bool h32, bool h16, bool h8, bool h4b) {
#pragma unroll
    for (int j = 0; j < 8; j++) {
        float snd = h32 ? a[j] : a[j + 8];
        float kp  = h32 ? a[j + 8] : a[j];
        a[j] = kp + __shfl_xor(snd, 32, 64);
    }
#pragma unroll
    for (int j = 0; j < 4; j++) {
        float snd = h16 ? a[j] : a[j + 4];
        float kp  = h16 ? a[j + 4] : a[j];
        a[j] = kp + __shfl_xor(snd, 16, 64);
    }
#pragma unroll
    for (int j = 0; j < 2; j++) {
        float snd = h8 ? a[j] : a[j + 2];
        float kp  = h8 ? a[j + 2] : a[j];
        a[j] = kp + __shfl_xor(snd, 8, 64);
    }
    {
        float snd = h4b ? a[0] : a[1];
        float kp  = h4b ? a[1] : a[0];
        a[0] = kp + __shfl_xor(snd, 4, 64);
    }
}

__global__ __launch_bounds__(NT) void enc_kernel(
    const float* __restrict__ dep, const float* __restrict__ ne,
    const float* __restrict__ gate_w, const float* __restrict__ gate_b,
    const float* __restrict__ map_w, const float* __restrict__ map_b,
    const float* __restrict__ w_ih, const float* __restrict__ w_hh,
    const float* __restrict__ b_ih, const float* __restrict__ b_hh,
    int* __restrict__ flags, uint* __restrict__ hv_ex, uint* __restrict__ hin_ex,
    float* __restrict__ out)
{
    // ~80 KiB LDS -> 1 block/CU
    __shared__ __align__(16) uint shm[20416];
    uint*  hvS   = shm;                       // [16][512] staged h (fp16 pairs)
    float* GM    = (float*)(shm + 8192);      // [2][16*4][65]: G,M rows (padded)
    float* red   = (float*)(shm + 16512);     // [3][512] cross-wave partials
    float* hbuf  = (float*)(shm + 18048);     // [64] h_in / hv per (b,o)
    float* hbuf2 = (float*)(shm + 18112);     // [64] scan partial (s != t-1)
    float* wihb  = (float*)(shm + 18176);     // [3][4][16] w_ih slice
    uint*  depb  = shm + 18368;               // [16][64][2] mask bits

    const int tid  = threadIdx.x;
    const int bid  = blockIdx.x;
    const int o0   = bid * 4;
    const int w    = tid >> 6;
    const int lane = tid & 63;
    const bool h32 = (lane & 32) != 0, h16 = (lane & 16) != 0;
    const bool h8  = (lane & 8) != 0,  h4b = (lane & 4) != 0;
    const int olw  = lane & 3;
    const int kseg = w * 16 + (lane >> 2);
    const int k0   = kseg * 8;

    // ---- weights -> 20 VGPRs/lane (unique slice, zero replication) ----
    uint wG[4], wM[4], wR[4], wZ[4], wN[4];
    loadw4(wG, gate_w + (o0 + olw) * 1024 + k0);
    loadw4(wM, map_w + (o0 + olw) * 1024 + k0);
    loadw4(wR, w_hh + (o0 + olw) * 1024 + k0);
    loadw4(wZ, w_hh + (1024 + o0 + olw) * 1024 + k0);
    loadw4(wN, w_hh + (2048 + o0 + olw) * 1024 + k0);

    // ---- LDS tables: dep bits (all 16 b), w_ih slice ----
#pragma unroll
    for (int e = 0; e < 4; e++) {
        int idx = tid + e * 512;
        int b = idx >> 7, tt = (idx >> 1) & 63, hf = idx & 1;
        const float4* dp = (const float4*)(dep + ((b * 64 + tt) * 64) + hf * 32);
        uint bits = 0;
#pragma unroll
        for (int s4 = 0; s4 < 8; s4++) {
            float4 v = dp[s4];
            bits |= (v.x != 0.0f) ? (1u << (s4 * 4 + 0)) : 0u;
            bits |= (v.y != 0.0f) ? (1u << (s4 * 4 + 1)) : 0u;
            bits |= (v.z != 0.0f) ? (1u << (s4 * 4 + 2)) : 0u;
            bits |= (v.w != 0.0f) ? (1u << (s4 * 4 + 3)) : 0u;
        }
        depb[idx] = bits;
    }
    if (tid < 192) {
        int g = tid >> 6, ol = (tid >> 4) & 3, c = tid & 15;
        wihb[tid] = w_ih[(g * 1024 + o0 + ol) * 16 + c];
    }

    // ---- hoisted per-thread scalars ----
    const int prS = tid >> 3;                // scan pair [0,64)
    const int bS = prS >> 2, olS = prS & 3, soct = tid & 7;
    const float gbS = gate_b[o0 + olS];
    const float mbS = map_b[o0 + olS];
    const float baseS = sigm(gbS) * mbS;
    const int bP = tid >> 2, olP = tid & 3, oP = o0 + olP;  // tid<64 roles
    const float gbP = gate_b[oP], mbP = map_b[oP];
    const float basP = sigm(gbP) * mbP;
    const float bir = b_ih[oP], biz = b_ih[1024 + oP], bin_ = b_ih[2048 + oP];
    const float bhr = b_hh[oP], bhz = b_hh[1024 + oP], bhn = b_hh[2048 + oP];
    __syncthreads();

    for (int t = 0; t < 64; t++) {
        const uint tagT = (uint)(t & 1);
        // ===== phase A pre-work: masked scan over s != t-1 (stable GM rows) =====
        {
            uint bl = depb[bS * 128 + t * 2 + (soct >> 2)];
            uint bits8 = (bl >> ((soct & 3) * 8)) & 0xFFu;
            int s0 = soct * 8;
            const float* Gp = GM + prS * 65;
            const float* Mp = GM + 4160 + prS * 65;
            float part = 0.0f;
#pragma unroll
            for (int j = 0; j < 8; j++) {
                int s = s0 + j;
                float Gv = Gp[s], Mv = Mp[s];
                float term = ((bits8 >> j) & 1u) ? (sigm(Gv + gbS) * (Mv + mbS)) : baseS;
                part += (s == t - 1) ? 0.0f : term;
            }
            part += __shfl_xor(part, 1, 64);
            part += __shfl_xor(part, 2, 64);
            part += __shfl_xor(part, 4, 64);
            if (soct == 0) hbuf2[prS] = part;
        }

        // ===== phase A: flags -> stage+verify hv(t-1), GEMV, finish h_in =====
        if (t > 0) {
            wait_flags(flags, 2 * t);                 // includes __syncthreads
            stagev4(hv_ex, hvS, tid, tagT ^ 1u);      // hv(t-1) tag = (t-1)&1
            __syncthreads();
            float aG[16], aM[16];
#pragma unroll
            for (int b = 0; b < 16; b++) { aG[b] = 0.0f; aM[b] = 0.0f; }
#pragma unroll
            for (int b = 0; b < 16; b++) {
                uint4v hq = *(const uint4v*)&hvS[b * 512 + kseg * 4];
#pragma unroll
                for (int q = 0; q < 4; q++) {
                    aG[b] = fdot2(wG[q], hq[q], aG[b]);
                    aM[b] = fdot2(wM[q], hq[q], aM[b]);
                }
            }
            rscat16(aG, h32, h16, h8, h4b);
            rscat16(aM, h32, h16, h8, h4b);
            red[w * 64 + lane]       = aG[0];
            red[512 + w * 64 + lane] = aM[0];
            __syncthreads();
            if (tid < 64) {
                float nG = 0.0f, nM = 0.0f;
#pragma unroll
                for (int ww = 0; ww < 8; ww++) {
                    nG += red[ww * 64 + tid];
                    nM += red[512 + ww * 64 + tid];
                }
                GM[tid * 65 + (t - 1)] = nG;
                GM[4160 + tid * 65 + (t - 1)] = nM;
                uint blb = depb[bP * 128 + t * 2 + ((t - 1) >> 5)];
                int bit = (blb >> ((t - 1) & 31)) & 1;
                float term = bit ? (sigm(nG + gbP) * (nM + mbP)) : basP;
                hbuf[tid] = hbuf2[tid] + term;
            }
        } else {
            __syncthreads();
            if (tid < 64) hbuf[tid] = hbuf2[tid];
        }
        // publish h_in + flag: all wave 0, same-wave program order (no barriers)
        if (tid < 16) {
            uint p0 = packh2(hbuf[tid * 4 + 0], hbuf[tid * 4 + 1]);
            uint p1 = packh2(hbuf[tid * 4 + 2], hbuf[tid * 4 + 3]);
            st_pub2(hin_ex + tid * 512 + bid * 2, p0, p1, tagT);
        }
        if (tid == 0) st_flag_noack(flags + bid, 2 * t + 1);

        // ===== phase B: gi (covers flight), flags -> stage+verify h_in, GRU =====
        float gi0 = 0.0f, gi1 = 0.0f, gi2 = 0.0f;
        if (tid < 64) {
            const float* xr = ne + (bP * 64 + t) * 16;
            float4 xa = ((const float4*)xr)[0];
            float4 xb = ((const float4*)xr)[1];
            float4 xc = ((const float4*)xr)[2];
            float4 xd = ((const float4*)xr)[3];
            const float4* w0p = (const float4*)&wihb[olP * 16];
            const float4* w1p = (const float4*)&wihb[64 + olP * 16];
            const float4* w2p = (const float4*)&wihb[128 + olP * 16];
            float4 a0 = w0p[0], a1 = w0p[1], a2 = w0p[2], a3 = w0p[3];
            gi0 = a0.x*xa.x + a0.y*xa.y + a0.z*xa.z + a0.w*xa.w
                + a1.x*xb.x + a1.y*xb.y + a1.z*xb.z + a1.w*xb.w
                + a2.x*xc.x + a2.y*xc.y + a2.z*xc.z + a2.w*xc.w
                + a3.x*xd.x + a3.y*xd.y + a3.z*xd.z + a3.w*xd.w;
            float4 b0 = w1p[0], b1 = w1p[1], b2 = w1p[2], b3 = w1p[3];
            gi1 = b0.x*xa.x + b0.y*xa.y + b0.z*xa.z + b0.w*xa.w
                + b1.x*xb.x + b1.y*xb.y + b1.z*xb.z + b1.w*xb.w
                + b2.x*xc.x + b2.y*xc.y + b2.z*xc.z + b2.w*xc.w
                + b3.x*xd.x + b3.y*xd.y + b3.z*xd.z + b3.w*xd.w;
            float4 c0 = w2p[0], c1 = w2p[1], c2 = w2p[2], c3 = w2p[3];
            gi2 = c0.x*xa.x + c0.y*xa.y + c0.z*xa.z + c0.w*xa.w
                + c1.x*xb.x + c1.y*xb.y + c1.z*xb.z + c1.w*xb.w
                + c2.x*xc.x + c2.y*xc.y + c2.z*xc.z + c2.w*xc.w
                + c3.x*xd.x + c3.y*xd.y + c3.z*xd.z + c3.w*xd.w;
        }
        wait_flags(flags, 2 * t + 1);
        stagev4(hin_ex, hvS, tid, tagT);              // h_in(t) tag = t&1
        __syncthreads();
        float aR[16], aZ[16], aN[16];
#pragma unroll
        for (int b = 0; b < 16; b++) { aR[b] = 0.0f; aZ[b] = 0.0f; aN[b] = 0.0f; }
#pragma unroll
        for (int b = 0; b < 16; b++) {
            uint4v hq = *(const uint4v*)&hvS[b * 512 + kseg * 4];
#pragma unroll
            for (int q = 0; q < 4; q++) {
                aR[b] = fdot2(wR[q], hq[q], aR[b]);
                aZ[b] = fdot2(wZ[q], hq[q], aZ[b]);
                aN[b] = fdot2(wN[q], hq[q], aN[b]);
            }
        }
        rscat16(aR, h32, h16, h8, h4b);
        rscat16(aZ, h32, h16, h8, h4b);
        rscat16(aN, h32, h16, h8, h4b);
        red[w * 64 + lane]        = aR[0];
        red[512 + w * 64 + lane]  = aZ[0];
        red[1024 + w * 64 + lane] = aN[0];
        __syncthreads();
        if (tid < 64) {
            float ghr = 0.0f, ghz = 0.0f, ghn = 0.0f;
#pragma unroll
            for (int ww = 0; ww < 8; ww++) {
                ghr += red[ww * 64 + tid];
                ghz += red[512 + ww * 64 + tid];
                ghn += red[1024 + ww * 64 + tid];
            }
            float h_in = hbuf[tid];
            float r = sigm(gi0 + bir + ghr + bhr);
            float z = sigm(gi1 + biz + ghz + bhz);
            float n = tanhfast(gi2 + bin_ + r * (ghn + bhn));
            float hv = (1.0f - z) * n + z * h_in;
            if (t == 63) out[bP * 1024 + oP] = hv;
            hbuf[tid] = hv;
        }
        // publish hv + flag: all wave 0, same-wave program order (no barriers)
        if (t < 63) {
            if (tid < 16) {
                uint p0 = packh2(hbuf[tid * 4 + 0], hbuf[tid * 4 + 1]);
                uint p1 = packh2(hbuf[tid * 4 + 2], hbuf[tid * 4 + 3]);
                st_pub2(hv_ex + tid * 512 + bid * 2, p0, p1, tagT);
            }
            if (tid == 0) st_flag_noack(flags + bid, 2 * t + 2);
        }
        __syncthreads();   // protect hbuf/GM before next iteration's writers
    }
    // mu/logvar computed by kF (separate dispatch) from the f32 hv in out.
}

__device__ __forceinline__ float wave_sum(float v) {
    v += __shfl_xor(v, 32, 64);
    v += __shfl_xor(v, 16, 64);
    v += __shfl_xor(v, 8, 64);
    v += __shfl_xor(v, 4, 64);
    v += __shfl_xor(v, 2, 64);
    v += __shfl_xor(v, 1, 64);
    return v;
}

// mu/logvar: out[16K..32K) = hv @ l1w^T + b1, out[32K..48K) = hv @ l2w^T + b2.
__global__ __launch_bounds__(256) void kF(
    float* out, const float* __restrict__ w1, const float* __restrict__ b1,
    const float* __restrict__ w2, const float* __restrict__ b2)
{
    const int wid = threadIdx.x >> 6;
    const int kl = threadIdx.x & 63;
    const int o = blockIdx.x * 2 + (wid >> 1);
    const int b0 = (wid & 1) * 8;

    float w1v[16], w2v[16];
#pragma unroll
    for (int i = 0; i < 16; i++) {
        w1v[i] = w1[o * 1024 + kl + 64 * i];
        w2v[i] = w2[o * 1024 + kl + 64 * i];
    }
    for (int b = b0; b < b0 + 8; b++) {
        float p1 = 0.0f, p2 = 0.0f;
#pragma unroll
        for (int i = 0; i < 16; i++) {
            float h = out[b * 1024 + kl + 64 * i];
            p1 += h * w1v[i];
            p2 += h * w2v[i];
        }
        p1 = wave_sum(p1);
        p2 = wave_sum(p2);
        if (kl == 0) {
            out[16384 + b * 1024 + o] = p1 + b1[o];
            out[32768 + b * 1024 + o] = p2 + b2[o];
        }
    }
}

extern "C" void kernel_launch(void* const* d_in, const int* in_sizes, int n_in,
                              void* d_out, int out_size, void* d_ws, size_t ws_size,
                              hipStream_t stream) {
    const float* dep     = (const float*)d_in[0];
    const float* ne      = (const float*)d_in[1];
    const float* gate_w  = (const float*)d_in[2];
    const float* gate_b  = (const float*)d_in[3];
    const float* map_w   = (const float*)d_in[4];
    const float* map_b   = (const float*)d_in[5];
    const float* w_ih    = (const float*)d_in[6];
    const float* w_hh    = (const float*)d_in[7];
    const float* b_ih    = (const float*)d_in[8];
    const float* b_hh    = (const float*)d_in[9];
    const float* lin11_w = (const float*)d_in[10];
    const float* lin11_b = (const float*)d_in[11];
    const float* lin12_w = (const float*)d_in[12];
    const float* lin12_b = (const float*)d_in[13];

    int* wsI = (int*)d_ws;
    int* flags   = wsI;                      // [256] ints
    uint* hv_ex  = (uint*)(wsI + 256);       // [16][512] uints
    uint* hin_ex = hv_ex + 8192;             // [16][512] uints
    float* outp  = (float*)d_out;

    hipMemsetAsync((void*)flags, 0, 256 * 4, stream);
    // tag-reset: all exchange uints -> LSB=1 (first real publishes use tag 0)
    hipMemsetAsync((void*)hv_ex, 0xFF, 2 * 8192 * 4, stream);

    void* args[] = {
        (void*)&dep, (void*)&ne, (void*)&gate_w, (void*)&gate_b,
        (void*)&map_w, (void*)&map_b, (void*)&w_ih, (void*)&w_hh,
        (void*)&b_ih, (void*)&b_hh,
        (void*)&flags, (void*)&hv_ex, (void*)&hin_ex, (void*)&outp,
    };
    hipError_t e = hipLaunchCooperativeKernel((void*)enc_kernel, dim3(NBLK), dim3(NT),
                                              args, 0, stream);
    if (e != hipSuccess) {
        enc_kernel<<<dim3(NBLK), dim3(NT), 0, stream>>>(
            dep, ne, gate_w, gate_b, map_w, map_b, w_ih, w_hh, b_ih, b_hh,
            flags, hv_ex, hin_ex, outp);
    }
    kF<<<dim3(512), dim3(256), 0, stream>>>(outp, lin11_w, lin11_b, lin12_w, lin12_b);
}